// Round 15
// baseline (59.532 us; speedup 1.0000x reference)
//
#include <hip/hip_runtime.h>

// LRFGraphConv: out[v] = ((nbr_sum[v] - deg[v]*verts[v]) @ lrf[v]) @ W^T + maxN*b
//
// R15 = R14 with ONE variable changed: accum_project's LDS accumulation goes
// from AoS float4 acc[64] shared by all waves (4 LDS atomics/pair, 8-way bank
// aliasing + same-address contention) to PER-WAVE REPLICATED SoA accumulators
// accs[8 waves][4][64] (zero inter-wave contention, ~2 lanes/bank conflict-
// free), 512 threads for gather latency hiding. Merge copies at the end.
//  K1 scatter (R14-identical): LDS hist + independent global atomic-return
//     per (block,range) + LDS ranks -> dense per-range segments.
//  K2 accum_project: replicated-SoA LDS accumulation, rotate, project, write.
//     maxN*b handled by on-device bias!=0 check (b==0 here -> skipped).

#define RBITS 6
#define RSIZE 64        // vertices per range
#define NRMAX 800       // bound for NR (= 782)
#define CAPR  1536      // pairs per range (mean ~1024, +16 sigma)
#define STHR  512
#define ATHR  512       // accum threads (8 waves)
#define NW    (ATHR / 64)

__global__ __launch_bounds__(512)
void scatter_kernel(const int* __restrict__ edges,
                    unsigned* __restrict__ cursor,   // [NRMAX] zeroed
                    unsigned* __restrict__ pairs,    // [NRMAX][CAPR]
                    int E, int NR) {
    __shared__ unsigned cnt[NRMAX];
    __shared__ unsigned cur[NRMAX];
    __shared__ unsigned bas[NRMAX];
    const int t = threadIdx.x;
    for (int i = t; i < NR; i += STHR) { cnt[i] = 0u; cur[i] = 0u; }
    __syncthreads();

    int i4 = blockIdx.x * STHR + t;
    int e0 = 2 * i4, e1 = e0 + 1;
    int rr[4]; unsigned pk[4]; int np = 0;
    if (e1 < E) {
        int4 e = ((const int4*)edges)[i4];
        rr[0] = e.x >> RBITS; pk[0] = ((unsigned)e.y << RBITS) | ((unsigned)e.x & (RSIZE - 1));
        rr[1] = e.y >> RBITS; pk[1] = ((unsigned)e.x << RBITS) | ((unsigned)e.y & (RSIZE - 1));
        rr[2] = e.z >> RBITS; pk[2] = ((unsigned)e.w << RBITS) | ((unsigned)e.z & (RSIZE - 1));
        rr[3] = e.w >> RBITS; pk[3] = ((unsigned)e.z << RBITS) | ((unsigned)e.w & (RSIZE - 1));
        np = 4;
    } else if (e0 < E) {
        int2 e = ((const int2*)edges)[e0];
        rr[0] = e.x >> RBITS; pk[0] = ((unsigned)e.y << RBITS) | ((unsigned)e.x & (RSIZE - 1));
        rr[1] = e.y >> RBITS; pk[1] = ((unsigned)e.x << RBITS) | ((unsigned)e.y & (RSIZE - 1));
        np = 2;
    }

    #pragma unroll
    for (int j = 0; j < 4; ++j)
        if (j < np) atomicAdd(&cnt[rr[j]], 1u);
    __syncthreads();

    for (int r = t; r < NR; r += STHR) {   // independent atomic-returns
        unsigned c = cnt[r];
        bas[r] = c ? atomicAdd(&cursor[r], c) : 0u;
    }
    __syncthreads();

    #pragma unroll
    for (int j = 0; j < 4; ++j)
        if (j < np) {
            int r = rr[j];
            unsigned s = bas[r] + atomicAdd(&cur[r], 1u);
            if (s < CAPR) pairs[(unsigned)r * CAPR + s] = pk[j];
        }
}

__global__ __launch_bounds__(ATHR)
void accum_project(const float* __restrict__ verts,
                   const float* __restrict__ lrf,
                   const float4* __restrict__ W4,     // W as float4[96]
                   const float4* __restrict__ bias4,  // bias as float4[32]
                   const unsigned* __restrict__ pairs,
                   const unsigned* __restrict__ cursor,
                   unsigned* __restrict__ done,
                   int* __restrict__ gmax,
                   float4* __restrict__ out4,         // [V*32]
                   int V, int NR) {
    __shared__ float accs[NW][4][RSIZE];   // per-wave SoA: [x|y|z|d][cl]
    __shared__ float rotL[RSIZE][3];
    __shared__ float degL[RSIZE];
    __shared__ int wm[NW];
    __shared__ int flagnz;
    const int r = blockIdx.x, t = threadIdx.x;
    const int wave = t >> 6;

    for (int i = t; i < NW * 4 * RSIZE; i += ATHR)
        ((float*)accs)[i] = 0.f;
    if (t == 0) flagnz = 0;
    __syncthreads();

    unsigned n = cursor[r];
    if (n > CAPR) n = CAPR;
    const unsigned* seg = pairs + (unsigned)r * CAPR;
    float (*ma)[RSIZE] = accs[wave];
    for (unsigned p = t; p < n; p += ATHR) {
        unsigned pk = seg[p];
        int nb = (int)(pk >> RBITS);
        int cl = (int)(pk & (RSIZE - 1));
        atomicAdd(&ma[0][cl], verts[3 * nb + 0]);
        atomicAdd(&ma[1][cl], verts[3 * nb + 1]);
        atomicAdd(&ma[2][cl], verts[3 * nb + 2]);
        atomicAdd(&ma[3][cl], 1.f);
    }
    if (t < 32) {   // bias nonzero check (wave 0)
        float4 bv = bias4[t];
        unsigned long long m =
            __ballot(bv.x != 0.f || bv.y != 0.f || bv.z != 0.f || bv.w != 0.f);
        if (t == 0 && m) flagnz = 1;
    }
    __syncthreads();

    int v0 = r << RBITS;
    int nv = min(RSIZE, V - v0);
    int d = 0;
    if (t < nv) {
        float sx = 0.f, sy = 0.f, sz = 0.f, sd = 0.f;
        #pragma unroll
        for (int w = 0; w < NW; ++w) {
            sx += accs[w][0][t];
            sy += accs[w][1][t];
            sz += accs[w][2][t];
            sd += accs[w][3][t];
        }
        int v = v0 + t;
        float s0 = sx - sd * verts[3 * v + 0];
        float s1 = sy - sd * verts[3 * v + 1];
        float s2 = sz - sd * verts[3 * v + 2];
        const float* L = lrf + (size_t)9 * v;
        rotL[t][0] = s0 * L[0] + s1 * L[3] + s2 * L[6];
        rotL[t][1] = s0 * L[1] + s1 * L[4] + s2 * L[7];
        rotL[t][2] = s0 * L[2] + s1 * L[5] + s2 * L[8];
        degL[t] = sd;
        d = (int)sd;
    }
    #pragma unroll
    for (int off = 32; off > 0; off >>= 1)
        d = max(d, __shfl_down(d, off, 64));
    if ((t & 63) == 0) wm[wave] = d;
    __syncthreads();
    if (t == 0) {
        int m = wm[0];
        #pragma unroll
        for (int w = 1; w < NW; ++w) m = max(m, wm[w]);
        atomicMax(gmax, m);
    }

    // projection (bias skipped; b==0 on this problem's inputs)
    const int NIT = nv * 32;
    for (int item = t; item < NIT; item += ATHR) {
        int lv = item >> 5;
        int q = item & 31;
        float r0 = rotL[lv][0], r1 = rotL[lv][1], r2 = rotL[lv][2];
        float4 w0 = W4[3 * q + 0];
        float4 w1 = W4[3 * q + 1];
        float4 w2 = W4[3 * q + 2];
        float4 o;
        o.x = r0 * w0.x + r1 * w0.y + r2 * w0.z;
        o.y = r0 * w0.w + r1 * w1.x + r2 * w1.y;
        o.z = r0 * w1.z + r1 * w1.w + r2 * w2.x;
        o.w = r0 * w2.y + r1 * w2.z + r2 * w2.w;
        out4[(size_t)(v0 + lv) * 32 + q] = o;
    }

    // b != 0 correctness fallback (never taken in this bench)
    if (flagnz) {
        __syncthreads();
        if (t == 0) {
            __threadfence();
            __hip_atomic_fetch_add(done, 1u, __ATOMIC_ACQ_REL, __HIP_MEMORY_SCOPE_AGENT);
            while (__hip_atomic_load(done, __ATOMIC_ACQUIRE, __HIP_MEMORY_SCOPE_AGENT) < (unsigned)NR)
                __builtin_amdgcn_s_sleep(32);
        }
        __syncthreads();
        float mx = (float)__hip_atomic_load(gmax, __ATOMIC_ACQUIRE, __HIP_MEMORY_SCOPE_AGENT);
        for (int item = t; item < NIT; item += ATHR) {
            int lv = item >> 5;
            int q = item & 31;
            float4 bv = bias4[q];
            size_t idx = (size_t)(v0 + lv) * 32 + q;
            float4 o = out4[idx];
            o.x += mx * bv.x; o.y += mx * bv.y;
            o.z += mx * bv.z; o.w += mx * bv.w;
            out4[idx] = o;
        }
    }
}

extern "C" void kernel_launch(void* const* d_in, const int* in_sizes, int n_in,
                              void* d_out, int out_size, void* d_ws, size_t ws_size,
                              hipStream_t stream) {
    const float* verts = (const float*)d_in[0];
    const int*   edges = (const int*)d_in[1];
    const float* lrf   = (const float*)d_in[2];
    const float* W     = (const float*)d_in[3];
    const float* bias  = (const float*)d_in[4];

    int V = in_sizes[0] / 3;
    int E = in_sizes[1] / 2;
    int NR = (V + RSIZE - 1) >> RBITS;          // 782
    int Ni4 = (E + 1) / 2;
    int NB = (Ni4 + STHR - 1) / STHR;           // 391 scatter blocks

    // ---- workspace layout ----
    // [done u32][gmax int][pad to 16][cursor NRMAX u32][pairs NRMAX*CAPR u32]
    char* ws = (char*)d_ws;
    unsigned* done   = (unsigned*)ws;
    int*      gmax   = (int*)(ws + 4);
    unsigned* cursor = (unsigned*)(ws + 16);
    unsigned* pairs  = (unsigned*)(ws + 16 + (size_t)NRMAX * 4);

    // zero done/gmax/cursors (3.2KB, one fill node)
    (void)hipMemsetAsync(d_ws, 0, 16 + (size_t)NRMAX * 4, stream);

    scatter_kernel<<<NB, STHR, 0, stream>>>(edges, cursor, pairs, E, NR);

    accum_project<<<NR, ATHR, 0, stream>>>(verts, lrf, (const float4*)W,
                                           (const float4*)bias, pairs, cursor,
                                           done, gmax, (float4*)d_out, V, NR);
}

// Round 16
// 57.209 us; speedup vs baseline: 1.0406x; 1.0406x over previous
//
#include <hip/hip_runtime.h>

// LRFGraphConv: out[v] = ((nbr_sum[v] - deg[v]*verts[v]) @ lrf[v]) @ W^T + maxN*b
//
// R16: TWO graph nodes total (no memset/fill node).
//  K1 scatter (R11-proven, deterministic, zero global atomics, zero pre-zero):
//     block = 1024 edges -> 2048 directed pairs; LDS bucket-sort by
//     center-range (RSIZE=256, NR=196) via LDS rank atomics + 256-wide scan;
//     flush block-private contiguous region COALESCED; write cnt[r][b],
//     off[r][b] tables with plain stores (fully overwritten every call).
//     Thread 0 of block 0 also zeroes done/gmax (used only by b!=0 fallback).
//  K2 accum_project (fused): block r stages cnt/off rows, prefix-scans in
//     LDS, binary-search work assignment, fp32 LDS accumulation, rotate by
//     lrf, project to 128 dims, write 32KB output slice. maxN*b handled by
//     on-device bias!=0 check (b==0 here -> term skipped; fallback never runs).

#define RBITS 8
#define RSIZE 256
#define STHR  512          // scatter threads (1 int4 = 2 edges each)
#define PPB   2048         // pairs per scatter block
#define NBMAX 512          // accum scan width (supports NB <= 512)
#define NRMAX 256

// ---------------- K1: block-local bucket sort + coalesced flush -------------
__global__ __launch_bounds__(512)
void scatter_kernel(const int* __restrict__ edges,
                    unsigned* __restrict__ cntg,   // [NR*NB]
                    unsigned* __restrict__ offg,   // [NR*NB]
                    unsigned* __restrict__ gpairs, // [NB*PPB]
                    unsigned* __restrict__ done,   // fallback counter
                    int* __restrict__ gmax,        // fallback max cell
                    int E, int NR, int NB) {
    __shared__ unsigned cnt[NRMAX];
    __shared__ unsigned sc[NRMAX];
    __shared__ unsigned stage[PPB];
    const int b = blockIdx.x, t = threadIdx.x;
    if (b == 0 && t == 0) { *done = 0u; *gmax = 0; }
    if (t < NRMAX) cnt[t] = 0u;
    __syncthreads();

    int i4 = b * STHR + t;
    int e0 = 2 * i4, e1 = e0 + 1;
    int rr[4]; unsigned pk[4]; unsigned rk[4]; int np = 0;
    if (e1 < E) {
        int4 e = ((const int4*)edges)[i4];
        rr[0] = e.x >> RBITS; pk[0] = ((unsigned)e.y << RBITS) | ((unsigned)e.x & (RSIZE - 1));
        rr[1] = e.y >> RBITS; pk[1] = ((unsigned)e.x << RBITS) | ((unsigned)e.y & (RSIZE - 1));
        rr[2] = e.z >> RBITS; pk[2] = ((unsigned)e.w << RBITS) | ((unsigned)e.z & (RSIZE - 1));
        rr[3] = e.w >> RBITS; pk[3] = ((unsigned)e.z << RBITS) | ((unsigned)e.w & (RSIZE - 1));
        np = 4;
    } else if (e0 < E) {
        int2 e = ((const int2*)edges)[e0];
        rr[0] = e.x >> RBITS; pk[0] = ((unsigned)e.y << RBITS) | ((unsigned)e.x & (RSIZE - 1));
        rr[1] = e.y >> RBITS; pk[1] = ((unsigned)e.x << RBITS) | ((unsigned)e.y & (RSIZE - 1));
        np = 2;
    }
    #pragma unroll
    for (int j = 0; j < 4; ++j)
        if (j < np) rk[j] = atomicAdd(&cnt[rr[j]], 1u);
    __syncthreads();

    // inclusive scan of cnt[0..255] -> sc (all threads hit barriers)
    if (t < NRMAX) sc[t] = cnt[t];
    __syncthreads();
    for (int d = 1; d < NRMAX; d <<= 1) {
        unsigned add = 0u;
        if (t < NRMAX && t >= d) add = sc[t - d];
        __syncthreads();
        if (t < NRMAX) sc[t] += add;
        __syncthreads();
    }

    #pragma unroll
    for (int j = 0; j < 4; ++j)
        if (j < np) stage[(sc[rr[j]] - cnt[rr[j]]) + rk[j]] = pk[j];
    __syncthreads();

    unsigned total = sc[NRMAX - 1];
    unsigned gbase = (unsigned)b * PPB;
    for (unsigned i = t; i < total; i += STHR)
        gpairs[gbase + i] = stage[i];
    if (t < NR) {
        cntg[t * NB + b] = cnt[t];
        offg[t * NB + b] = sc[t] - cnt[t];
    }
}

// ---------------- K2: accum + rotate + project (fused) ----------------------
__global__ __launch_bounds__(512)
void accum_project(const float* __restrict__ verts,
                   const float* __restrict__ lrf,
                   const float4* __restrict__ W4,     // W as float4[96]
                   const float4* __restrict__ bias4,  // bias as float4[32]
                   const unsigned* __restrict__ cntg,
                   const unsigned* __restrict__ offg,
                   const unsigned* __restrict__ gpairs,
                   unsigned* __restrict__ done,
                   int* __restrict__ gmax,
                   float4* __restrict__ out4,         // [V*32]
                   int V, int NB, int NR) {
    __shared__ float4 acc[RSIZE];
    __shared__ float rotL[RSIZE][3];
    __shared__ unsigned C[NBMAX], O[NBMAX], S[NBMAX];
    __shared__ int wm[8];
    __shared__ int flagnz;
    const int r = blockIdx.x, t = threadIdx.x;

    if (t < RSIZE) acc[t] = make_float4(0.f, 0.f, 0.f, 0.f);
    if (t == 0) flagnz = 0;
    unsigned c = 0u;
    if (t < NB) { c = cntg[r * NB + t]; O[t] = offg[r * NB + t]; }
    C[t] = c; S[t] = c;
    __syncthreads();
    for (int d = 1; d < NBMAX; d <<= 1) {
        unsigned add = (t >= d) ? S[t - d] : 0u;
        __syncthreads();
        S[t] += add;
        __syncthreads();
    }
    unsigned T = S[NBMAX - 1];

    for (unsigned i = t; i < T; i += 512) {
        int lo = 0, hi = NBMAX - 1;          // smallest b with S[b] > i
        while (lo < hi) { int mid = (lo + hi) >> 1; if (S[mid] > i) hi = mid; else lo = mid + 1; }
        unsigned local = i - (S[lo] - C[lo]);
        unsigned pk = gpairs[(unsigned)lo * PPB + O[lo] + local];
        int nb = (int)(pk >> RBITS);
        int cl = (int)(pk & (RSIZE - 1));
        float* ap = (float*)&acc[cl];
        atomicAdd(ap + 0, verts[3 * nb + 0]);
        atomicAdd(ap + 1, verts[3 * nb + 1]);
        atomicAdd(ap + 2, verts[3 * nb + 2]);
        atomicAdd(ap + 3, 1.f);
    }
    if (t < 32) {   // bias nonzero check (wave 0)
        float4 bv = bias4[t];
        unsigned long long m =
            __ballot(bv.x != 0.f || bv.y != 0.f || bv.z != 0.f || bv.w != 0.f);
        if (t == 0 && m) flagnz = 1;
    }
    __syncthreads();

    int v0 = r << RBITS;
    int nv = min(RSIZE, V - v0);
    int d = 0;
    if (t < nv) {
        float4 a = acc[t];
        int v = v0 + t;
        float s0 = a.x - a.w * verts[3 * v + 0];
        float s1 = a.y - a.w * verts[3 * v + 1];
        float s2 = a.z - a.w * verts[3 * v + 2];
        const float* L = lrf + (size_t)9 * v;
        rotL[t][0] = s0 * L[0] + s1 * L[3] + s2 * L[6];
        rotL[t][1] = s0 * L[1] + s1 * L[4] + s2 * L[7];
        rotL[t][2] = s0 * L[2] + s1 * L[5] + s2 * L[8];
        d = (int)a.w;
    }
    __syncthreads();

    // projection (bias skipped; b==0 on this problem's inputs)
    const int NIT = nv * 32;
    for (int item = t; item < NIT; item += 512) {
        int lv = item >> 5;
        int q = item & 31;
        float r0 = rotL[lv][0], r1 = rotL[lv][1], r2 = rotL[lv][2];
        float4 w0 = W4[3 * q + 0];
        float4 w1 = W4[3 * q + 1];
        float4 w2 = W4[3 * q + 2];
        float4 o;
        o.x = r0 * w0.x + r1 * w0.y + r2 * w0.z;
        o.y = r0 * w0.w + r1 * w1.x + r2 * w1.y;
        o.z = r0 * w1.z + r1 * w1.w + r2 * w2.x;
        o.w = r0 * w2.y + r1 * w2.z + r2 * w2.w;
        out4[(size_t)(v0 + lv) * 32 + q] = o;
    }

    // b != 0 correctness fallback (never taken in this bench)
    if (flagnz) {
        #pragma unroll
        for (int off = 32; off > 0; off >>= 1)
            d = max(d, __shfl_down(d, off, 64));
        if ((t & 63) == 0) wm[t >> 6] = d;
        __syncthreads();
        if (t == 0) {
            int m = wm[0];
            #pragma unroll
            for (int w = 1; w < 8; ++w) m = max(m, wm[w]);
            atomicMax(gmax, m);
            __threadfence();
            __hip_atomic_fetch_add(done, 1u, __ATOMIC_ACQ_REL, __HIP_MEMORY_SCOPE_AGENT);
            while (__hip_atomic_load(done, __ATOMIC_ACQUIRE, __HIP_MEMORY_SCOPE_AGENT) < (unsigned)NR)
                __builtin_amdgcn_s_sleep(32);
        }
        __syncthreads();
        float mx = (float)__hip_atomic_load(gmax, __ATOMIC_ACQUIRE, __HIP_MEMORY_SCOPE_AGENT);
        for (int item = t; item < NIT; item += 512) {
            int lv = item >> 5;
            int q = item & 31;
            float4 bv = bias4[q];
            size_t idx = (size_t)(v0 + lv) * 32 + q;
            float4 o = out4[idx];
            o.x += mx * bv.x; o.y += mx * bv.y;
            o.z += mx * bv.z; o.w += mx * bv.w;
            out4[idx] = o;
        }
    }
}

extern "C" void kernel_launch(void* const* d_in, const int* in_sizes, int n_in,
                              void* d_out, int out_size, void* d_ws, size_t ws_size,
                              hipStream_t stream) {
    const float* verts = (const float*)d_in[0];
    const int*   edges = (const int*)d_in[1];
    const float* lrf   = (const float*)d_in[2];
    const float* W     = (const float*)d_in[3];
    const float* bias  = (const float*)d_in[4];

    int V = in_sizes[0] / 3;
    int E = in_sizes[1] / 2;
    int NR = (V + RSIZE - 1) >> RBITS;          // 196 ranges
    int Ni4 = (E + 1) / 2;                      // int4 granules
    int NB = (Ni4 + STHR - 1) / STHR;           // 391 scatter blocks (<=512)

    // ---- workspace layout (all fully rewritten every call) ----
    // [done u32][gmax int][pad16][cntg NR*NB][offg NR*NB][pad][gpairs NB*PPB]
    char* ws = (char*)d_ws;
    unsigned* done = (unsigned*)ws;
    int*      gmax = (int*)(ws + 4);
    size_t off = 16;
    unsigned* cntg = (unsigned*)(ws + off);  off += (size_t)NR * NB * 4;
    unsigned* offg = (unsigned*)(ws + off);  off += (size_t)NR * NB * 4;
    off = (off + 15) & ~(size_t)15;
    unsigned* gpairs = (unsigned*)(ws + off);

    scatter_kernel<<<NB, STHR, 0, stream>>>(edges, cntg, offg, gpairs,
                                            done, gmax, E, NR, NB);

    accum_project<<<NR, 512, 0, stream>>>(verts, lrf, (const float4*)W,
                                          (const float4*)bias, cntg, offg,
                                          gpairs, done, gmax,
                                          (float4*)d_out, V, NB, NR);
}